// Round 17
// baseline (108.569 us; speedup 1.0000x reference)
//
#include <hip/hip_runtime.h>
#include <hip/hip_fp16.h>
#include <math.h>

#define NN 1024
#define CC 200
#define AA 256

static constexpr float P_EXP = 0.8f;
static constexpr float Q_EXP = 2.0f;
static constexpr float EPS_C = 0.01f;

typedef __attribute__((ext_vector_type(8))) _Float16 half8;
typedef __attribute__((ext_vector_type(4))) _Float16 half4v;
typedef __attribute__((ext_vector_type(4))) float f32x4;

// ---------------- prep: W->fp16 (208 rows, zero pad) + counts ----------------
__global__ void k_prep(const float* __restrict__ W, const int* __restrict__ lab,
                       _Float16* __restrict__ Whf, float* __restrict__ accv){
  if (blockIdx.x == 52){
    __shared__ int cnt[CC];
    int t = threadIdx.x;
    for (int i = t; i < CC; i += 256) cnt[i] = 0;
    __syncthreads();
    for (int n = t; n < NN; n += 256) atomicAdd(&cnt[lab[n]], 1);
    __syncthreads();
    for (int i = t; i < CC; i += 256) accv[i] = fmaxf((float)cnt[i], 1.0f);
    return;
  }
  int idx = (blockIdx.x * 256 + threadIdx.x) * 4;
  if (idx >= 208 * AA) return;
  float4 w = make_float4(0.f, 0.f, 0.f, 0.f);
  if (idx < CC * AA) w = *(const float4*)(W + idx);
  Whf[idx + 0] = (_Float16)w.x;
  Whf[idx + 1] = (_Float16)w.y;
  Whf[idx + 2] = (_Float16)w.z;
  Whf[idx + 3] = (_Float16)w.w;
}

// ---------------- quadratic form + shift: (a-half, l) per block ----------------
// 400 blocks x 256 thr (4 waves, 2 blocks co-residable/CU). R9's proven schedule
// (gload_lds linear dest + source swizzle, depth-1 prefetch, __syncthreads), but
// 4 waves x 4 c-chains: LDS read amplification 8x -> 4x (R16 diagnostic: probe
// hit 5.8 TB/s and L3-warm didn't help k_quad => the wall is the 2MB/block LDS
// re-read, not memory). E-frags register-hoisted (ef[4][8]).
// MFMA1: M'[a,c]=sum_b CV[a,b]E[c,b]; MFMA2: D2 += diag_c(E[c',a](M'+2dm)),
// dm sliced per half (disjoint -> unconditional). Halves write disjoint slabs.
__global__ __launch_bounds__(256) void k_quad(
    const _Float16* __restrict__ Whf, const float* __restrict__ CV,
    const float* __restrict__ ms, const float* __restrict__ mtg,
    const float* __restrict__ lamp, float* __restrict__ tbl)
{
  const int ah   = blockIdx.x;          // a-half 0/1 (8 tiles each)
  const int l    = blockIdx.y;
  const int tid  = threadIdx.x;
  const int wid  = tid >> 6;
  const int lane = tid & 63;
  const int lrow = lane & 15;
  const int kgrp = lane >> 4;

  __shared__ float4 cvb[2][16][64];     // 2 x 16KB double buffer
  __shared__ _Float16 dmh[128];         // 2*(mt-ms), this half's a-range

  if (tid < 128)
    dmh[tid] = (_Float16)(2.f * (mtg[l * AA + ah * 128 + tid] - ms[l * AA + ah * 128 + tid]));

  // ---- E fragments register-hoisted: wave owns ct = wid + 4k (covers 13) ----
  half8 ef[4][8];
  #pragma unroll
  for (int kt = 0; kt < 8; ++kt){
    half8 wlv = *(const half8*)(Whf + l * AA + kt * 32 + kgrp * 8);
    #pragma unroll
    for (int k = 0; k < 4; ++k){
      const int ct = wid + k * 4;
      const int crow = (ct < 13) ? (ct * 16 + lrow) : lrow;  // pad-safe dummy
      half8 wcf = *(const half8*)(Whf + crow * AA + kt * 32 + kgrp * 8);
      ef[k][kt] = wcf - wlv;
    }
  }

  const size_t cvbase = (size_t)l * AA * AA + (size_t)ah * 128 * AA;

  // stage tile -> buf: wave wid loads rows {4wid..4wid+3}; LDS linear dest,
  // global source pre-swizzled within the row (slot ^ (row&7)).
  #define STAGE(TILE, BUF) do {                                               \
    _Pragma("unroll")                                                         \
    for (int rr_ = 0; rr_ < 4; ++rr_){                                        \
      int row_ = wid * 4 + rr_;                                               \
      const float* gs_ = CV + cvbase + (size_t)(TILE) * 16 * AA               \
                       + (size_t)row_ * AA + ((lane ^ (row_ & 7)) << 2);      \
      __builtin_amdgcn_global_load_lds(                                       \
        (const __attribute__((address_space(1))) void*)gs_,                   \
        (__attribute__((address_space(3))) void*)&cvb[BUF][row_][0],          \
        16, 0, 0);                                                            \
    }                                                                         \
  } while(0)

  STAGE(0, 0);
  __syncthreads();                      // tile0 + dmh ready

  f32x4 D2[4];
  #pragma unroll
  for (int k = 0; k < 4; ++k) D2[k] = (f32x4){0.f,0.f,0.f,0.f};
  const float lam = lamp[0];

  for (int t = 0; t < 8; ++t){
    if (t + 1 < 8) STAGE(t + 1, (t + 1) & 1);   // issue-early, overlaps compute

    // ---- MFMA1 over this tile: 4 independent c-chains per wave ----
    const int buf = t & 1;
    f32x4 a[4];
    #pragma unroll
    for (int k = 0; k < 4; ++k) a[k] = (f32x4){0.f,0.f,0.f,0.f};

    #pragma unroll
    for (int kt = 0; kt < 8; ++kt){
      const int j0 = kt * 8 + kgrp * 2;
      float4 v0 = cvb[buf][lrow][( j0     ) ^ (lrow & 7)];
      float4 v1 = cvb[buf][lrow][( j0 + 1 ) ^ (lrow & 7)];
      half8 cvf;
      cvf[0]=(_Float16)v0.x; cvf[1]=(_Float16)v0.y; cvf[2]=(_Float16)v0.z; cvf[3]=(_Float16)v0.w;
      cvf[4]=(_Float16)v1.x; cvf[5]=(_Float16)v1.y; cvf[6]=(_Float16)v1.z; cvf[7]=(_Float16)v1.w;
      #pragma unroll
      for (int k = 0; k < 4; ++k){
        const int ct = wid + k * 4;
        if (ct < 13)
          a[k] = __builtin_amdgcn_mfma_f32_16x16x32_f16(cvf, ef[k][kt], a[k], 0, 0, 0);
      }
    }

    // ---- MFMA2: contract this tile's a-slice into D2 (+ this half's shift) ----
    const int aslg = ah * 128 + t * 16 + kgrp * 4;
    half4v wl2 = *(const half4v*)(Whf + l * AA + aslg);
    half4v dmf = *(const half4v*)&dmh[t * 16 + kgrp * 4];
    #pragma unroll
    for (int k = 0; k < 4; ++k){
      const int ct = wid + k * 4;
      if (ct < 13){
        half4v wc2 = *(const half4v*)(Whf + (ct * 16 + lrow) * AA + aslg);
        half4v e2  = wc2 - wl2;
        half4v b2;
        b2[0]=(_Float16)a[k][0]; b2[1]=(_Float16)a[k][1];
        b2[2]=(_Float16)a[k][2]; b2[3]=(_Float16)a[k][3];
        D2[k] = __builtin_amdgcn_mfma_f32_16x16x16f16(e2, b2,  D2[k], 0, 0, 0);
        D2[k] = __builtin_amdgcn_mfma_f32_16x16x16f16(e2, dmf, D2[k], 0, 0, 0);
      }
    }

    __syncthreads();                    // tile t reads done; stage(t+1) drained
  }

  // diag extraction: lane holds D2[m=kgrp*4+jj][n=lrow]; diag at kgrp*4+jj==lrow
  if ((lrow >> 2) == kgrp){
    const int jj = lrow & 3;
    #pragma unroll
    for (int k = 0; k < 4; ++k){
      const int ct = wid + k * 4;
      const int c  = ct * 16 + lrow;
      if (ct < 13 && c < CC){
        float d = (jj == 0) ? D2[k][0] : (jj == 1) ? D2[k][1]
                : (jj == 2) ? D2[k][2] : D2[k][3];
        tbl[(size_t)ah * CC * CC + l * CC + c] = 0.5f * lam * d;
      }
    }
  }
  #undef STAGE
}

// ---------------- per-row seesaw loss (sums 2 half-slabs) ----------------
__global__ __launch_bounds__(64) void k_rows(
    const float* __restrict__ ys, const int* __restrict__ lab,
    const float* __restrict__ accv, const float* __restrict__ tbl,
    float* __restrict__ nll)
{
  const int n    = blockIdx.x;
  const int lane = threadIdx.x;
  const int l    = lab[n];
  const float acc_l = accv[l];
  const float log_acc_l = logf(acc_l);

  float z[4];
  float m = -1e30f;
  #pragma unroll
  for (int k = 0; k < 4; k++){
    int cidx = k * 64 + lane;
    float zz = -1e30f;
    if (cidx < CC)
      zz = ys[n * CC + cidx] + tbl[l * CC + cidx] + tbl[CC * CC + l * CC + cidx];
    z[k] = zz;
    m = fmaxf(m, zz);
  }
  for (int o = 32; o; o >>= 1) m = fmaxf(m, __shfl_xor(m, o));

  float se = 0.f;
  #pragma unroll
  for (int k = 0; k < 4; k++){
    int cidx = k * 64 + lane;
    if (cidx < CC) se += expf(z[k] - m);
  }
  for (int o = 32; o; o >>= 1) se += __shfl_xor(se, o);
  const float L0 = m + logf(se);

  const int kl = l >> 6, ll = l & 63;
  float zsel = (kl == 0) ? z[0] : (kl == 1 ? z[1] : (kl == 2 ? z[2] : z[3]));
  const float zl = __shfl(zsel, ll);
  const float logden = fmaxf(zl - L0, logf(EPS_C));

  float lg[4];
  float m2 = -1e30f;
  #pragma unroll
  for (int k = 0; k < 4; k++){
    int cidx = k * 64 + lane;
    float lz = -1e30f;
    if (cidx < CC){
      lz = z[k];
      if (cidx != l){
        float lratio = (z[k] - L0) - logden;
        float lcomp  = (lratio > 0.f) ? Q_EXP * lratio : 0.f;
        float accc   = accv[cidx];
        float lmit   = (accc < acc_l) ? P_EXP * (logf(accc) - log_acc_l) : 0.f;
        lz += lcomp + lmit;
      }
    }
    lg[k] = lz;
    m2 = fmaxf(m2, lz);
  }
  for (int o = 32; o; o >>= 1) m2 = fmaxf(m2, __shfl_xor(m2, o));
  float se2 = 0.f;
  #pragma unroll
  for (int k = 0; k < 4; k++){
    int cidx = k * 64 + lane;
    if (cidx < CC) se2 += expf(lg[k] - m2);
  }
  for (int o = 32; o; o >>= 1) se2 += __shfl_xor(se2, o);
  const float L1 = m2 + logf(se2);

  if (lane == 0) nll[n] = L1 - zl;
}

// ---------------- mean ----------------
__global__ void k_mean(const float* __restrict__ nll, float* __restrict__ out){
  __shared__ float s[256];
  int t = threadIdx.x;
  float v = 0.f;
  for (int i = t; i < NN; i += 256) v += nll[i];
  s[t] = v; __syncthreads();
  for (int o = 128; o; o >>= 1){ if (t < o) s[t] += s[t + o]; __syncthreads(); }
  if (t == 0) out[0] = s[0] / (float)NN;
}

extern "C" void kernel_launch(void* const* d_in, const int* in_sizes, int n_in,
                              void* d_out, int out_size, void* d_ws, size_t ws_size,
                              hipStream_t stream) {
  const float* W   = (const float*)d_in[0];
  const float* ys  = (const float*)d_in[2];
  const int*   lab = (const int*)  d_in[3];
  const float* lam = (const float*)d_in[4];
  const float* ms  = (const float*)d_in[5];
  const float* mt  = (const float*)d_in[6];
  const float* CV  = (const float*)d_in[7];

  float* ws   = (float*)d_ws;
  float* tbl  = ws;                          // 2 x 40000 (half slabs, fully overwritten)
  float* accv = ws + 80000;                  // 256
  float* nll  = ws + 80256;                  // 1024
  _Float16* Whf = (_Float16*)(ws + 81280);   // 208*256 fp16
  float* out  = (float*)d_out;

  k_prep <<<53, 256, 0, stream>>>(W, lab, Whf, accv);
  dim3 gq(2, CC);
  k_quad <<<gq, 256, 0, stream>>>(Whf, CV, ms, mt, lam, tbl);
  k_rows <<<NN, 64, 0, stream>>>(ys, lab, accv, tbl, nll);
  k_mean <<<1, 256, 0, stream>>>(nll, out);
}